// Round 8
// baseline (484.828 us; speedup 1.0000x reference)
//
#include <hip/hip_runtime.h>
#include <hip/hip_fp16.h>
#include <math.h>

#define D_IN  256
#define D_H   64
#define D_OUT 16

// ---------------------------------------------------------------------------
// GEMM1: h1[n,64] = x[n,256] @ W1[256,64], output fp16.
// v3: latency-bound fix (rounds 5/6 both 97us, VALUBusy 26%, no pipe >30%):
//  - W1 fp16 in LDS (32 KB) -> 4 blocks/CU x 8 waves = full occupancy
//    (was 64 KB fp32 -> 2 blocks/CU; LDS was the occupancy cap, and low
//    TLP couldn't hide ~600cy x-load latency)
//  - 512 thr/block, 2 rows x 4 cols/thread, grid 1563 (good shape, no tail)
//  - explicit next-iter x prefetch (2 loads in flight/wave)
// ---------------------------------------------------------------------------
__global__ __launch_bounds__(512) void k_gemm1(const float* __restrict__ x,
                                               const float* __restrict__ W1,
                                               __half* __restrict__ h1h, int n) {
    __shared__ __half2 w1s[D_IN * D_H / 2];  // 32 KB, [k][colpair] colpair=c/2
    int t = threadIdx.x;
    for (int i = t; i < D_IN * D_H / 2; i += 512) {
        float2 w = ((const float2*)W1)[i];
        w1s[i] = __floats2half2_rn(w.x, w.y);
    }
    __syncthreads();

    int cgrp = t & 15;                         // cols cgrp*4 .. cgrp*4+3
    int rbase = blockIdx.x * 64 + (t >> 4) * 2;  // 2 rows per thread
    int r0 = min(rbase, n - 1);
    int r1 = min(rbase + 1, n - 1);
    const float4* xr0 = (const float4*)(x + (size_t)r0 * D_IN);
    const float4* xr1 = (const float4*)(x + (size_t)r1 * D_IN);

    float4 a0 = {0.f, 0.f, 0.f, 0.f}, a1 = {0.f, 0.f, 0.f, 0.f};
    float4 c0 = xr0[0], c1 = xr1[0];

#define GFMA4(K4)                                                            \
    {                                                                        \
        _Pragma("unroll")                                                    \
        for (int kk = 0; kk < 4; ++kk) {                                     \
            __half2 w01 = w1s[((K4) * 4 + kk) * 32 + cgrp * 2];              \
            __half2 w23 = w1s[((K4) * 4 + kk) * 32 + cgrp * 2 + 1];         \
            float wx = __low2float(w01), wy = __high2float(w01);             \
            float wz = __low2float(w23), ww = __high2float(w23);             \
            float s0 = (&c0.x)[kk], s1 = (&c1.x)[kk];                        \
            a0.x = fmaf(s0, wx, a0.x); a0.y = fmaf(s0, wy, a0.y);            \
            a0.z = fmaf(s0, wz, a0.z); a0.w = fmaf(s0, ww, a0.w);            \
            a1.x = fmaf(s1, wx, a1.x); a1.y = fmaf(s1, wy, a1.y);            \
            a1.z = fmaf(s1, wz, a1.z); a1.w = fmaf(s1, ww, a1.w);            \
        }                                                                    \
    }

#pragma unroll 4
    for (int k4 = 0; k4 < D_IN / 4 - 1; ++k4) {
        float4 n0 = xr0[k4 + 1];    // prefetch next iter's rows
        float4 n1 = xr1[k4 + 1];
        GFMA4(k4);
        c0 = n0; c1 = n1;
    }
    GFMA4(D_IN / 4 - 1);            // peeled last iter (no prefetch)
#undef GFMA4

    if (rbase < n) {
        __half2* o2 = (__half2*)(h1h + (size_t)rbase * D_H);
        o2[cgrp * 2 + 0] = __floats2half2_rn(a0.x, a0.y);
        o2[cgrp * 2 + 1] = __floats2half2_rn(a0.z, a0.w);
    }
    if (rbase + 1 < n) {
        __half2* o2 = (__half2*)(h1h + (size_t)(rbase + 1) * D_H);
        o2[cgrp * 2 + 0] = __floats2half2_rn(a1.x, a1.y);
        o2[cgrp * 2 + 1] = __floats2half2_rn(a1.z, a1.w);
    }
}

// ---------------------------------------------------------------------------
// CSR build: histogram -> 2-level exclusive scan -> XCD-phased scatter
// ---------------------------------------------------------------------------
__global__ void k_hist(const int* __restrict__ ei, int* __restrict__ counts, int e_cnt) {
    int e = blockIdx.x * blockDim.x + threadIdx.x;
    if (e < e_cnt) atomicAdd(&counts[ei[e]], 1);  // ei[0..E) = dst row
}

__global__ __launch_bounds__(256) void k_scanA(const int* __restrict__ counts,
                                               int* __restrict__ exOut,
                                               int* __restrict__ blockSum, int n) {
    __shared__ int lds[256];
    int t = threadIdx.x;
    int base = blockIdx.x * 1024 + t * 4;
    int c0 = (base + 0 < n) ? counts[base + 0] : 0;
    int c1 = (base + 1 < n) ? counts[base + 1] : 0;
    int c2 = (base + 2 < n) ? counts[base + 2] : 0;
    int c3 = (base + 3 < n) ? counts[base + 3] : 0;
    int tsum = c0 + c1 + c2 + c3;
    lds[t] = tsum;
    __syncthreads();
    for (int off = 1; off < 256; off <<= 1) {
        int v = (t >= off) ? lds[t - off] : 0;
        __syncthreads();
        lds[t] += v;
        __syncthreads();
    }
    int exBase = lds[t] - tsum;
    if (t == 0) blockSum[blockIdx.x] = lds[255];
    if (base + 0 < n) exOut[base + 0] = exBase;
    if (base + 1 < n) exOut[base + 1] = exBase + c0;
    if (base + 2 < n) exOut[base + 2] = exBase + c0 + c1;
    if (base + 3 < n) exOut[base + 3] = exBase + c0 + c1 + c2;
}

__global__ __launch_bounds__(128) void k_scanB(const int* __restrict__ blockSum,
                                               int* __restrict__ blockOff,
                                               int* __restrict__ offsets, int nb, int n) {
    __shared__ int lds[128];
    int t = threadIdx.x;
    int v = (t < nb) ? blockSum[t] : 0;
    lds[t] = v;
    __syncthreads();
    for (int off = 1; off < 128; off <<= 1) {
        int u = (t >= off) ? lds[t - off] : 0;
        __syncthreads();
        lds[t] += u;
        __syncthreads();
    }
    if (t < nb) blockOff[t] = lds[t] - v;
    if (t == 127) offsets[n] = lds[127];
}

__global__ void k_scanC(const int* __restrict__ exOut, const int* __restrict__ blockOff,
                        int* __restrict__ offsets, int* __restrict__ cursor, int n) {
    int i = blockIdx.x * blockDim.x + threadIdx.x;
    if (i < n) {
        int v = exOut[i] + blockOff[i >> 10];
        offsets[i] = v;
        cursor[i] = v;
    }
}

// XCD-phased scatter (verified round 5: k_scatter left top-5, was 135us).
__global__ __launch_bounds__(256) void k_scatter(const int* __restrict__ ei,
                                                 const float* __restrict__ vals,
                                                 int* __restrict__ cursor,
                                                 int2* __restrict__ srcval,
                                                 int e_cnt, int bucketDiv,
                                                 int blocksPerPass) {
    int pass = blockIdx.x & 7;
    int bchunk = blockIdx.x >> 3;
    int lo = pass * bucketDiv;
    int stride = blocksPerPass * 256;
    for (int e = bchunk * 256 + threadIdx.x; e < e_cnt; e += stride) {
        int d = ei[e];
        if ((unsigned)(d - lo) < (unsigned)bucketDiv) {
            int s = ei[e_cnt + e];
            float v = vals[e];
            int p = atomicAdd(&cursor[d], 1);
            srcval[p] = make_int2(s, __float_as_int(v));
        }
    }
}

// ---------------------------------------------------------------------------
// Fused SpMM1 + ReLU + GEMM2, one wave per dst row; edge loop unrolled x8.
// ---------------------------------------------------------------------------
__global__ __launch_bounds__(256) void k_spmm1g2(const int* __restrict__ offsets,
                                                 const int2* __restrict__ sv,
                                                 const __half* __restrict__ h1h,
                                                 const float* __restrict__ W2,
                                                 __half* __restrict__ h2h, int n) {
    __shared__ float W2s[D_H * 17];
    __shared__ float rbuf[4][D_H];
    int t = threadIdx.x;
    for (int i = t; i < D_H * D_OUT; i += 256)
        W2s[(i >> 4) * 17 + (i & 15)] = W2[i];

    int lane = t & 63, wid = t >> 6;
    int dst = blockIdx.x * 4 + wid;
    bool valid = dst < n;
    int e0 = 0, e1 = 0;
    if (valid) { e0 = offsets[dst]; e1 = offsets[dst + 1]; }

    float acc = 0.f;
    int e = e0;
    for (; e + 8 <= e1; e += 8) {
        int2 A0 = sv[e + 0], A1 = sv[e + 1], A2 = sv[e + 2], A3 = sv[e + 3];
        int2 A4 = sv[e + 4], A5 = sv[e + 5], A6 = sv[e + 6], A7 = sv[e + 7];
        float g0 = __half2float(h1h[(size_t)A0.x * D_H + lane]);
        float g1 = __half2float(h1h[(size_t)A1.x * D_H + lane]);
        float g2 = __half2float(h1h[(size_t)A2.x * D_H + lane]);
        float g3 = __half2float(h1h[(size_t)A3.x * D_H + lane]);
        float g4 = __half2float(h1h[(size_t)A4.x * D_H + lane]);
        float g5 = __half2float(h1h[(size_t)A5.x * D_H + lane]);
        float g6 = __half2float(h1h[(size_t)A6.x * D_H + lane]);
        float g7 = __half2float(h1h[(size_t)A7.x * D_H + lane]);
        acc = fmaf(__int_as_float(A0.y), g0, acc);
        acc = fmaf(__int_as_float(A1.y), g1, acc);
        acc = fmaf(__int_as_float(A2.y), g2, acc);
        acc = fmaf(__int_as_float(A3.y), g3, acc);
        acc = fmaf(__int_as_float(A4.y), g4, acc);
        acc = fmaf(__int_as_float(A5.y), g5, acc);
        acc = fmaf(__int_as_float(A6.y), g6, acc);
        acc = fmaf(__int_as_float(A7.y), g7, acc);
    }
    for (; e < e1; ++e) {
        int2 A = sv[e];
        acc = fmaf(__int_as_float(A.y), __half2float(h1h[(size_t)A.x * D_H + lane]), acc);
    }
    rbuf[wid][lane] = fmaxf(acc, 0.f);
    __syncthreads();

    int j = lane & 15, g = lane >> 4;
    float s = 0.f;
#pragma unroll
    for (int kk = 0; kk < 16; ++kk)
        s = fmaf(rbuf[wid][g * 16 + kk], W2s[(g * 16 + kk) * 17 + j], s);
    s += __shfl_xor(s, 16);
    s += __shfl_xor(s, 32);
    if (valid && lane < 16) h2h[(size_t)dst * D_OUT + j] = __float2half(s);
}

// ---------------------------------------------------------------------------
// SpMM2 + log_softmax, 16 lanes per dst, edge loop unrolled x4.
// ---------------------------------------------------------------------------
__global__ __launch_bounds__(256) void k_spmm2(const int* __restrict__ offsets,
                                               const int2* __restrict__ sv,
                                               const __half* __restrict__ h2h,
                                               float* __restrict__ out, int n) {
    int t = threadIdx.x;
    int f = t & 15;
    int dst = blockIdx.x * 16 + (t >> 4);
    if (dst >= n) return;
    int e0 = offsets[dst], e1 = offsets[dst + 1];
    float acc = 0.f;
    int e = e0;
    for (; e + 4 <= e1; e += 4) {
        int2 A = sv[e], B = sv[e + 1], C = sv[e + 2], D = sv[e + 3];
        float g0 = __half2float(h2h[(size_t)A.x * D_OUT + f]);
        float g1 = __half2float(h2h[(size_t)B.x * D_OUT + f]);
        float g2 = __half2float(h2h[(size_t)C.x * D_OUT + f]);
        float g3 = __half2float(h2h[(size_t)D.x * D_OUT + f]);
        acc = fmaf(__int_as_float(A.y), g0, acc);
        acc = fmaf(__int_as_float(B.y), g1, acc);
        acc = fmaf(__int_as_float(C.y), g2, acc);
        acc = fmaf(__int_as_float(D.y), g3, acc);
    }
    for (; e < e1; ++e) {
        int2 A = sv[e];
        acc = fmaf(__int_as_float(A.y), __half2float(h2h[(size_t)A.x * D_OUT + f]), acc);
    }
    float m = acc;
#pragma unroll
    for (int d = 1; d < 16; d <<= 1) m = fmaxf(m, __shfl_xor(m, d, 16));
    float ex = expf(acc - m);
    float sum = ex;
#pragma unroll
    for (int d = 1; d < 16; d <<= 1) sum += __shfl_xor(sum, d, 16);
    out[(size_t)dst * D_OUT + f] = acc - m - logf(sum);
}

// ---------------------------------------------------------------------------
extern "C" void kernel_launch(void* const* d_in, const int* in_sizes, int n_in,
                              void* d_out, int out_size, void* d_ws, size_t ws_size,
                              hipStream_t stream) {
    const float* x  = (const float*)d_in[0];
    const float* W1 = (const float*)d_in[1];
    const float* W2 = (const float*)d_in[2];
    const float* ev = (const float*)d_in[3];
    const int*   ei = (const int*)d_in[4];
    float* out = (float*)d_out;

    int n     = in_sizes[0] / D_IN;  // 100000
    int e_cnt = in_sizes[3];         // 1600000

    int2*   srcval = (int2*)d_ws;                       // e_cnt
    __half* h1h    = (__half*)(srcval + e_cnt);         // n*64
    __half* h2h    = h1h + (size_t)n * D_H;             // n*16
    int* counts    = (int*)(h2h + (size_t)n * D_OUT);   // n
    int* exOut     = counts + n;                        // n
    int* blockSum  = exOut + n;                         // <=128
    int* blockOff  = blockSum + 128;                    // <=128
    int* offsets   = blockOff + 128;                    // n+1
    int* cursor    = offsets + n + 1;                   // n

    hipMemsetAsync(counts, 0, (size_t)n * sizeof(int), stream);

    int nb_scan = (n + 1023) / 1024;
    int bucketDiv = (n + 7) / 8;         // dst range per XCD pass
    int blocksPerPass = 256;             // grid = 8*256 = 2048 blocks

    k_gemm1  <<<(n + 63) / 64, 512, 0, stream>>>(x, W1, h1h, n);
    k_hist   <<<(e_cnt + 255) / 256, 256, 0, stream>>>(ei, counts, e_cnt);
    k_scanA  <<<nb_scan, 256, 0, stream>>>(counts, exOut, blockSum, n);
    k_scanB  <<<1, 128, 0, stream>>>(blockSum, blockOff, offsets, nb_scan, n);
    k_scanC  <<<(n + 255) / 256, 256, 0, stream>>>(exOut, blockOff, offsets, cursor, n);
    k_scatter<<<8 * blocksPerPass, 256, 0, stream>>>(ei, ev, cursor, srcval, e_cnt,
                                                     bucketDiv, blocksPerPass);
    k_spmm1g2<<<(n + 3) / 4, 256, 0, stream>>>(offsets, srcval, h1h, W2, h2h, n);
    k_spmm2  <<<(n + 15) / 16, 256, 0, stream>>>(offsets, srcval, h2h, out, n);
}

// Round 9
// 442.338 us; speedup vs baseline: 1.0961x; 1.0961x over previous
//
#include <hip/hip_runtime.h>
#include <hip/hip_fp16.h>
#include <math.h>

#define D_IN  256
#define D_H   64
#define D_OUT 16

typedef _Float16 f16x8 __attribute__((ext_vector_type(8)));
typedef float    f32x4 __attribute__((ext_vector_type(4)));

// ---------------------------------------------------------------------------
// GEMM1 v4 (MFMA): h1[n,64] = x[n,256] @ W1[256,64], fp16 in/out of MFMA.
// Rounds 5/6/8: three vector variants all 97-106us -> invariant bottleneck is
// the 16-lane broadcast x-load (64-128B unique per dwordx4, <=2 loads in
// flight). MFMA fragments make all 64 lanes load distinct 32B slices: a wave
// ingests a 16x32 x-subtile (2KB unique) per k-step, 16 loads in flight.
//  - W1 fp16 transposed [col][k+pad] in LDS (33.8KB, 4 blocks/CU)
//  - per-wave B-frags preloaded to registers once (8 frags = 32 VGPR)
//  - grid-stride over 16-row tiles; 8 MFMA + 16 dwordx4 loads per tile
// Frag mapping (m89/m97-verified convention): A lane: row=l&15,
// k=kstep*32+(l>>4)*8+j (8 consecutive); B lane: col=l&15, same k slice;
// C/D: col=l&15, row=(l>>4)*4+reg.
// ---------------------------------------------------------------------------
__global__ __launch_bounds__(256) void k_gemm1(const float* __restrict__ x,
                                               const float* __restrict__ W1,
                                               __half* __restrict__ h1h, int n) {
    __shared__ _Float16 w1t[D_H][264];   // [col][k], pad 256->264 halves
    int t = threadIdx.x;
    for (int i = t; i < D_IN * D_H; i += 256) {
        int k = i >> 6, c = i & 63;      // W1 row-major [k][c], coalesced read
        w1t[c][k] = (_Float16)W1[i];
    }
    __syncthreads();

    int l = t & 63, w = t >> 6;          // lane, wave(=col tile)
    int lrow = l & 15, lkg = l >> 4;     // frag row/col index, k-group
    int col = w * 16 + lrow;

    // preload 8 B-frags for this wave's 16 cols (registers, once)
    f16x8 bf[8];
#pragma unroll
    for (int ks = 0; ks < 8; ++ks)
        bf[ks] = *(const f16x8*)&w1t[col][ks * 32 + lkg * 8];

    int ntiles = (n + 15) >> 4;
    for (int rt = blockIdx.x; rt < ntiles; rt += gridDim.x) {
        int rbase = rt * 16;
        int row = min(rbase + lrow, n - 1);
        const float4* xr4 = (const float4*)(x + (size_t)row * D_IN);

        // issue all 16 A loads (8 ksteps x 2 float4) -> 16 in flight
        float4 p[16];
#pragma unroll
        for (int ks = 0; ks < 8; ++ks) {
            p[2 * ks + 0] = xr4[ks * 8 + lkg * 2 + 0];
            p[2 * ks + 1] = xr4[ks * 8 + lkg * 2 + 1];
        }

        f32x4 acc = {0.f, 0.f, 0.f, 0.f};
#pragma unroll
        for (int ks = 0; ks < 8; ++ks) {
            f16x8 af;
            af[0] = (_Float16)p[2 * ks].x;     af[1] = (_Float16)p[2 * ks].y;
            af[2] = (_Float16)p[2 * ks].z;     af[3] = (_Float16)p[2 * ks].w;
            af[4] = (_Float16)p[2 * ks + 1].x; af[5] = (_Float16)p[2 * ks + 1].y;
            af[6] = (_Float16)p[2 * ks + 1].z; af[7] = (_Float16)p[2 * ks + 1].w;
            acc = __builtin_amdgcn_mfma_f32_16x16x32_f16(af, bf[ks], acc, 0, 0, 0);
        }

#pragma unroll
        for (int reg = 0; reg < 4; ++reg) {
            int r = rbase + lkg * 4 + reg;
            if (r < n) h1h[(size_t)r * D_H + col] = __float2half(acc[reg]);
        }
    }
}

// ---------------------------------------------------------------------------
// CSR build: histogram -> 2-level exclusive scan -> XCD-phased scatter
// ---------------------------------------------------------------------------
__global__ void k_hist(const int* __restrict__ ei, int* __restrict__ counts, int e_cnt) {
    int e = blockIdx.x * blockDim.x + threadIdx.x;
    if (e < e_cnt) atomicAdd(&counts[ei[e]], 1);  // ei[0..E) = dst row
}

__global__ __launch_bounds__(256) void k_scanA(const int* __restrict__ counts,
                                               int* __restrict__ exOut,
                                               int* __restrict__ blockSum, int n) {
    __shared__ int lds[256];
    int t = threadIdx.x;
    int base = blockIdx.x * 1024 + t * 4;
    int c0 = (base + 0 < n) ? counts[base + 0] : 0;
    int c1 = (base + 1 < n) ? counts[base + 1] : 0;
    int c2 = (base + 2 < n) ? counts[base + 2] : 0;
    int c3 = (base + 3 < n) ? counts[base + 3] : 0;
    int tsum = c0 + c1 + c2 + c3;
    lds[t] = tsum;
    __syncthreads();
    for (int off = 1; off < 256; off <<= 1) {
        int v = (t >= off) ? lds[t - off] : 0;
        __syncthreads();
        lds[t] += v;
        __syncthreads();
    }
    int exBase = lds[t] - tsum;
    if (t == 0) blockSum[blockIdx.x] = lds[255];
    if (base + 0 < n) exOut[base + 0] = exBase;
    if (base + 1 < n) exOut[base + 1] = exBase + c0;
    if (base + 2 < n) exOut[base + 2] = exBase + c0 + c1;
    if (base + 3 < n) exOut[base + 3] = exBase + c0 + c1 + c2;
}

__global__ __launch_bounds__(128) void k_scanB(const int* __restrict__ blockSum,
                                               int* __restrict__ blockOff,
                                               int* __restrict__ offsets, int nb, int n) {
    __shared__ int lds[128];
    int t = threadIdx.x;
    int v = (t < nb) ? blockSum[t] : 0;
    lds[t] = v;
    __syncthreads();
    for (int off = 1; off < 128; off <<= 1) {
        int u = (t >= off) ? lds[t - off] : 0;
        __syncthreads();
        lds[t] += u;
        __syncthreads();
    }
    if (t < nb) blockOff[t] = lds[t] - v;
    if (t == 127) offsets[n] = lds[127];
}

__global__ void k_scanC(const int* __restrict__ exOut, const int* __restrict__ blockOff,
                        int* __restrict__ offsets, int* __restrict__ cursor, int n) {
    int i = blockIdx.x * blockDim.x + threadIdx.x;
    if (i < n) {
        int v = exOut[i] + blockOff[i >> 10];
        offsets[i] = v;
        cursor[i] = v;
    }
}

// XCD-phased scatter (verified round 5: k_scatter left top-5, was 135us).
__global__ __launch_bounds__(256) void k_scatter(const int* __restrict__ ei,
                                                 const float* __restrict__ vals,
                                                 int* __restrict__ cursor,
                                                 int2* __restrict__ srcval,
                                                 int e_cnt, int bucketDiv,
                                                 int blocksPerPass) {
    int pass = blockIdx.x & 7;
    int bchunk = blockIdx.x >> 3;
    int lo = pass * bucketDiv;
    int stride = blocksPerPass * 256;
    for (int e = bchunk * 256 + threadIdx.x; e < e_cnt; e += stride) {
        int d = ei[e];
        if ((unsigned)(d - lo) < (unsigned)bucketDiv) {
            int s = ei[e_cnt + e];
            float v = vals[e];
            int p = atomicAdd(&cursor[d], 1);
            srcval[p] = make_int2(s, __float_as_int(v));
        }
    }
}

// ---------------------------------------------------------------------------
// Fused SpMM1 + ReLU + GEMM2, one wave per dst row; edge loop unrolled x8.
// ---------------------------------------------------------------------------
__global__ __launch_bounds__(256) void k_spmm1g2(const int* __restrict__ offsets,
                                                 const int2* __restrict__ sv,
                                                 const __half* __restrict__ h1h,
                                                 const float* __restrict__ W2,
                                                 __half* __restrict__ h2h, int n) {
    __shared__ float W2s[D_H * 17];
    __shared__ float rbuf[4][D_H];
    int t = threadIdx.x;
    for (int i = t; i < D_H * D_OUT; i += 256)
        W2s[(i >> 4) * 17 + (i & 15)] = W2[i];

    int lane = t & 63, wid = t >> 6;
    int dst = blockIdx.x * 4 + wid;
    bool valid = dst < n;
    int e0 = 0, e1 = 0;
    if (valid) { e0 = offsets[dst]; e1 = offsets[dst + 1]; }

    float acc = 0.f;
    int e = e0;
    for (; e + 8 <= e1; e += 8) {
        int2 A0 = sv[e + 0], A1 = sv[e + 1], A2 = sv[e + 2], A3 = sv[e + 3];
        int2 A4 = sv[e + 4], A5 = sv[e + 5], A6 = sv[e + 6], A7 = sv[e + 7];
        float g0 = __half2float(h1h[(size_t)A0.x * D_H + lane]);
        float g1 = __half2float(h1h[(size_t)A1.x * D_H + lane]);
        float g2 = __half2float(h1h[(size_t)A2.x * D_H + lane]);
        float g3 = __half2float(h1h[(size_t)A3.x * D_H + lane]);
        float g4 = __half2float(h1h[(size_t)A4.x * D_H + lane]);
        float g5 = __half2float(h1h[(size_t)A5.x * D_H + lane]);
        float g6 = __half2float(h1h[(size_t)A6.x * D_H + lane]);
        float g7 = __half2float(h1h[(size_t)A7.x * D_H + lane]);
        acc = fmaf(__int_as_float(A0.y), g0, acc);
        acc = fmaf(__int_as_float(A1.y), g1, acc);
        acc = fmaf(__int_as_float(A2.y), g2, acc);
        acc = fmaf(__int_as_float(A3.y), g3, acc);
        acc = fmaf(__int_as_float(A4.y), g4, acc);
        acc = fmaf(__int_as_float(A5.y), g5, acc);
        acc = fmaf(__int_as_float(A6.y), g6, acc);
        acc = fmaf(__int_as_float(A7.y), g7, acc);
    }
    for (; e < e1; ++e) {
        int2 A = sv[e];
        acc = fmaf(__int_as_float(A.y), __half2float(h1h[(size_t)A.x * D_H + lane]), acc);
    }
    rbuf[wid][lane] = fmaxf(acc, 0.f);
    __syncthreads();

    int j = lane & 15, g = lane >> 4;
    float s = 0.f;
#pragma unroll
    for (int kk = 0; kk < 16; ++kk)
        s = fmaf(rbuf[wid][g * 16 + kk], W2s[(g * 16 + kk) * 17 + j], s);
    s += __shfl_xor(s, 16);
    s += __shfl_xor(s, 32);
    if (valid && lane < 16) h2h[(size_t)dst * D_OUT + j] = __float2half(s);
}

// ---------------------------------------------------------------------------
// SpMM2 + log_softmax, 16 lanes per dst, edge loop unrolled x4.
// ---------------------------------------------------------------------------
__global__ __launch_bounds__(256) void k_spmm2(const int* __restrict__ offsets,
                                               const int2* __restrict__ sv,
                                               const __half* __restrict__ h2h,
                                               float* __restrict__ out, int n) {
    int t = threadIdx.x;
    int f = t & 15;
    int dst = blockIdx.x * 16 + (t >> 4);
    if (dst >= n) return;
    int e0 = offsets[dst], e1 = offsets[dst + 1];
    float acc = 0.f;
    int e = e0;
    for (; e + 4 <= e1; e += 4) {
        int2 A = sv[e], B = sv[e + 1], C = sv[e + 2], D = sv[e + 3];
        float g0 = __half2float(h2h[(size_t)A.x * D_OUT + f]);
        float g1 = __half2float(h2h[(size_t)B.x * D_OUT + f]);
        float g2 = __half2float(h2h[(size_t)C.x * D_OUT + f]);
        float g3 = __half2float(h2h[(size_t)D.x * D_OUT + f]);
        acc = fmaf(__int_as_float(A.y), g0, acc);
        acc = fmaf(__int_as_float(B.y), g1, acc);
        acc = fmaf(__int_as_float(C.y), g2, acc);
        acc = fmaf(__int_as_float(D.y), g3, acc);
    }
    for (; e < e1; ++e) {
        int2 A = sv[e];
        acc = fmaf(__int_as_float(A.y), __half2float(h2h[(size_t)A.x * D_OUT + f]), acc);
    }
    float m = acc;
#pragma unroll
    for (int d = 1; d < 16; d <<= 1) m = fmaxf(m, __shfl_xor(m, d, 16));
    float ex = expf(acc - m);
    float sum = ex;
#pragma unroll
    for (int d = 1; d < 16; d <<= 1) sum += __shfl_xor(sum, d, 16);
    out[(size_t)dst * D_OUT + f] = acc - m - logf(sum);
}

// ---------------------------------------------------------------------------
extern "C" void kernel_launch(void* const* d_in, const int* in_sizes, int n_in,
                              void* d_out, int out_size, void* d_ws, size_t ws_size,
                              hipStream_t stream) {
    const float* x  = (const float*)d_in[0];
    const float* W1 = (const float*)d_in[1];
    const float* W2 = (const float*)d_in[2];
    const float* ev = (const float*)d_in[3];
    const int*   ei = (const int*)d_in[4];
    float* out = (float*)d_out;

    int n     = in_sizes[0] / D_IN;  // 100000
    int e_cnt = in_sizes[3];         // 1600000

    int2*   srcval = (int2*)d_ws;                       // e_cnt
    __half* h1h    = (__half*)(srcval + e_cnt);         // n*64
    __half* h2h    = h1h + (size_t)n * D_H;             // n*16
    int* counts    = (int*)(h2h + (size_t)n * D_OUT);   // n
    int* exOut     = counts + n;                        // n
    int* blockSum  = exOut + n;                         // <=128
    int* blockOff  = blockSum + 128;                    // <=128
    int* offsets   = blockOff + 128;                    // n+1
    int* cursor    = offsets + n + 1;                   // n

    hipMemsetAsync(counts, 0, (size_t)n * sizeof(int), stream);

    int nb_scan = (n + 1023) / 1024;
    int bucketDiv = (n + 7) / 8;         // dst range per XCD pass
    int blocksPerPass = 256;             // grid = 8*256 = 2048 blocks

    k_gemm1  <<<1024, 256, 0, stream>>>(x, W1, h1h, n);
    k_hist   <<<(e_cnt + 255) / 256, 256, 0, stream>>>(ei, counts, e_cnt);
    k_scanA  <<<nb_scan, 256, 0, stream>>>(counts, exOut, blockSum, n);
    k_scanB  <<<1, 128, 0, stream>>>(blockSum, blockOff, offsets, nb_scan, n);
    k_scanC  <<<(n + 255) / 256, 256, 0, stream>>>(exOut, blockOff, offsets, cursor, n);
    k_scatter<<<8 * blocksPerPass, 256, 0, stream>>>(ei, ev, cursor, srcval, e_cnt,
                                                     bucketDiv, blocksPerPass);
    k_spmm1g2<<<(n + 3) / 4, 256, 0, stream>>>(offsets, srcval, h1h, W2, h2h, n);
    k_spmm2  <<<(n + 15) / 16, 256, 0, stream>>>(offsets, srcval, h2h, out, n);
}

// Round 10
// 433.572 us; speedup vs baseline: 1.1182x; 1.0202x over previous
//
#include <hip/hip_runtime.h>
#include <hip/hip_fp16.h>
#include <math.h>

#define D_IN  256
#define D_H   64
#define D_OUT 16

typedef _Float16 f16x8 __attribute__((ext_vector_type(8)));
typedef float    f32x4 __attribute__((ext_vector_type(4)));

// ---------------------------------------------------------------------------
// GEMM1 v4 (MFMA) — verified round 9 (left top-5; was 97-106us as vector GEMM).
// ---------------------------------------------------------------------------
__global__ __launch_bounds__(256) void k_gemm1(const float* __restrict__ x,
                                               const float* __restrict__ W1,
                                               __half* __restrict__ h1h, int n) {
    __shared__ _Float16 w1t[D_H][264];   // [col][k], pad 256->264 halves
    int t = threadIdx.x;
    for (int i = t; i < D_IN * D_H; i += 256) {
        int k = i >> 6, c = i & 63;
        w1t[c][k] = (_Float16)W1[i];
    }
    __syncthreads();

    int l = t & 63, w = t >> 6;
    int lrow = l & 15, lkg = l >> 4;
    int col = w * 16 + lrow;

    f16x8 bf[8];
#pragma unroll
    for (int ks = 0; ks < 8; ++ks)
        bf[ks] = *(const f16x8*)&w1t[col][ks * 32 + lkg * 8];

    int ntiles = (n + 15) >> 4;
    for (int rt = blockIdx.x; rt < ntiles; rt += gridDim.x) {
        int rbase = rt * 16;
        int row = min(rbase + lrow, n - 1);
        const float4* xr4 = (const float4*)(x + (size_t)row * D_IN);

        float4 p[16];
#pragma unroll
        for (int ks = 0; ks < 8; ++ks) {
            p[2 * ks + 0] = xr4[ks * 8 + lkg * 2 + 0];
            p[2 * ks + 1] = xr4[ks * 8 + lkg * 2 + 1];
        }

        f32x4 acc = {0.f, 0.f, 0.f, 0.f};
#pragma unroll
        for (int ks = 0; ks < 8; ++ks) {
            f16x8 af;
            af[0] = (_Float16)p[2 * ks].x;     af[1] = (_Float16)p[2 * ks].y;
            af[2] = (_Float16)p[2 * ks].z;     af[3] = (_Float16)p[2 * ks].w;
            af[4] = (_Float16)p[2 * ks + 1].x; af[5] = (_Float16)p[2 * ks + 1].y;
            af[6] = (_Float16)p[2 * ks + 1].z; af[7] = (_Float16)p[2 * ks + 1].w;
            acc = __builtin_amdgcn_mfma_f32_16x16x32_f16(af, bf[ks], acc, 0, 0, 0);
        }

#pragma unroll
        for (int reg = 0; reg < 4; ++reg) {
            int r = rbase + lkg * 4 + reg;
            if (r < n) h1h[(size_t)r * D_H + col] = __float2half(acc[reg]);
        }
    }
}

// ---------------------------------------------------------------------------
// CSR build: histogram -> 2-level exclusive scan -> XCD-phased scatter
// ---------------------------------------------------------------------------
__global__ void k_hist(const int* __restrict__ ei, int* __restrict__ counts, int e_cnt) {
    int e = blockIdx.x * blockDim.x + threadIdx.x;
    if (e < e_cnt) atomicAdd(&counts[ei[e]], 1);  // ei[0..E) = dst row
}

__global__ __launch_bounds__(256) void k_scanA(const int* __restrict__ counts,
                                               int* __restrict__ exOut,
                                               int* __restrict__ blockSum, int n) {
    __shared__ int lds[256];
    int t = threadIdx.x;
    int base = blockIdx.x * 1024 + t * 4;
    int c0 = (base + 0 < n) ? counts[base + 0] : 0;
    int c1 = (base + 1 < n) ? counts[base + 1] : 0;
    int c2 = (base + 2 < n) ? counts[base + 2] : 0;
    int c3 = (base + 3 < n) ? counts[base + 3] : 0;
    int tsum = c0 + c1 + c2 + c3;
    lds[t] = tsum;
    __syncthreads();
    for (int off = 1; off < 256; off <<= 1) {
        int v = (t >= off) ? lds[t - off] : 0;
        __syncthreads();
        lds[t] += v;
        __syncthreads();
    }
    int exBase = lds[t] - tsum;
    if (t == 0) blockSum[blockIdx.x] = lds[255];
    if (base + 0 < n) exOut[base + 0] = exBase;
    if (base + 1 < n) exOut[base + 1] = exBase + c0;
    if (base + 2 < n) exOut[base + 2] = exBase + c0 + c1;
    if (base + 3 < n) exOut[base + 3] = exBase + c0 + c1 + c2;
}

__global__ __launch_bounds__(128) void k_scanB(const int* __restrict__ blockSum,
                                               int* __restrict__ blockOff,
                                               int* __restrict__ offsets, int nb, int n) {
    __shared__ int lds[128];
    int t = threadIdx.x;
    int v = (t < nb) ? blockSum[t] : 0;
    lds[t] = v;
    __syncthreads();
    for (int off = 1; off < 128; off <<= 1) {
        int u = (t >= off) ? lds[t - off] : 0;
        __syncthreads();
        lds[t] += u;
        __syncthreads();
    }
    if (t < nb) blockOff[t] = lds[t] - v;
    if (t == 127) offsets[n] = lds[127];
}

__global__ void k_scanC(const int* __restrict__ exOut, const int* __restrict__ blockOff,
                        int* __restrict__ offsets, int* __restrict__ cursor, int n) {
    int i = blockIdx.x * blockDim.x + threadIdx.x;
    if (i < n) {
        int v = exOut[i] + blockOff[i >> 10];
        offsets[i] = v;
        cursor[i] = v;
    }
}

// XCD-phased scatter (verified round 5: left top-5, was 135us).
__global__ __launch_bounds__(256) void k_scatter(const int* __restrict__ ei,
                                                 const float* __restrict__ vals,
                                                 int* __restrict__ cursor,
                                                 int2* __restrict__ srcval,
                                                 int e_cnt, int bucketDiv,
                                                 int blocksPerPass) {
    int pass = blockIdx.x & 7;
    int bchunk = blockIdx.x >> 3;
    int lo = pass * bucketDiv;
    int stride = blocksPerPass * 256;
    for (int e = bchunk * 256 + threadIdx.x; e < e_cnt; e += stride) {
        int d = ei[e];
        if ((unsigned)(d - lo) < (unsigned)bucketDiv) {
            int s = ei[e_cnt + e];
            float v = vals[e];
            int p = atomicAdd(&cursor[d], 1);
            srcval[p] = make_int2(s, __float_as_int(v));
        }
    }
}

// ---------------------------------------------------------------------------
// Fused SpMM1 + ReLU + GEMM2 v2: 2 edges per load instruction.
// Round-9 counters: 89us, VALUBusy 34%, HBM 12% -> mixed issue+latency bound.
// Lane l = edge-slot (l>>5) x feature-pair (l&31): one __half2 load covers
// 2 edges per wave instruction (was 1); sv loads + addr VALU halve too.
// Slot-reduce via shfl_xor(32), then ReLU + GEMM2 epilogue as before.
// ---------------------------------------------------------------------------
__global__ __launch_bounds__(256) void k_spmm1g2(const int* __restrict__ offsets,
                                                 const int2* __restrict__ sv,
                                                 const __half* __restrict__ h1h,
                                                 const float* __restrict__ W2,
                                                 __half* __restrict__ h2h, int n) {
    __shared__ float W2s[D_H * 17];
    __shared__ float rbuf[4][D_H];
    int t = threadIdx.x;
    for (int i = t; i < D_H * D_OUT; i += 256)
        W2s[(i >> 4) * 17 + (i & 15)] = W2[i];

    int lane = t & 63, wid = t >> 6;
    int dst = blockIdx.x * 4 + wid;
    bool valid = dst < n;
    int e0 = 0, e1 = 0;
    if (valid) { e0 = offsets[dst]; e1 = offsets[dst + 1]; }

    int s = lane >> 5;           // edge slot (0/1)
    int p = lane & 31;           // feature pair -> features 2p, 2p+1
    float ax = 0.f, ay = 0.f;
    int e = e0;
    // main: 8 edges (4 slot-pairs) per iteration; loads issued first for MLP
    for (; e + 8 <= e1; e += 8) {
        int2 A0 = sv[e + 0 + s];
        int2 A1 = sv[e + 2 + s];
        int2 A2 = sv[e + 4 + s];
        int2 A3 = sv[e + 6 + s];
        __half2 g0 = *(const __half2*)&h1h[(size_t)A0.x * D_H + 2 * p];
        __half2 g1 = *(const __half2*)&h1h[(size_t)A1.x * D_H + 2 * p];
        __half2 g2 = *(const __half2*)&h1h[(size_t)A2.x * D_H + 2 * p];
        __half2 g3 = *(const __half2*)&h1h[(size_t)A3.x * D_H + 2 * p];
        float v0 = __int_as_float(A0.y), v1 = __int_as_float(A1.y);
        float v2 = __int_as_float(A2.y), v3 = __int_as_float(A3.y);
        ax = fmaf(v0, __low2float(g0), ax); ay = fmaf(v0, __high2float(g0), ay);
        ax = fmaf(v1, __low2float(g1), ax); ay = fmaf(v1, __high2float(g1), ay);
        ax = fmaf(v2, __low2float(g2), ax); ay = fmaf(v2, __high2float(g2), ay);
        ax = fmaf(v3, __low2float(g3), ax); ay = fmaf(v3, __high2float(g3), ay);
    }
    // tail: slot-pairs with per-slot guard
    for (; e < e1; e += 2) {
        int ee = e + s;
        bool ok = ee < e1;
        int2 A = sv[ok ? ee : e];
        float v = ok ? __int_as_float(A.y) : 0.f;
        __half2 g = *(const __half2*)&h1h[(size_t)A.x * D_H + 2 * p];
        ax = fmaf(v, __low2float(g), ax);
        ay = fmaf(v, __high2float(g), ay);
    }
    // reduce across the 2 edge slots
    ax += __shfl_xor(ax, 32);
    ay += __shfl_xor(ay, 32);
    if (lane < 32) {
        rbuf[wid][2 * p + 0] = fmaxf(ax, 0.f);   // relu
        rbuf[wid][2 * p + 1] = fmaxf(ay, 0.f);
    }
    __syncthreads();

    // GEMM2 epilogue: h2[dst][j] = sum_k rbuf[k] * W2[k][j]
    int j = lane & 15, g = lane >> 4;
    float sacc = 0.f;
#pragma unroll
    for (int kk = 0; kk < 16; ++kk)
        sacc = fmaf(rbuf[wid][g * 16 + kk], W2s[(g * 16 + kk) * 17 + j], sacc);
    sacc += __shfl_xor(sacc, 16);
    sacc += __shfl_xor(sacc, 32);
    if (valid && lane < 16) h2h[(size_t)dst * D_OUT + j] = __float2half(sacc);
}

// ---------------------------------------------------------------------------
// SpMM2 + log_softmax v2: one wave per dst; 8 edge-slots x 8 feature-pairs.
// One __half2 load covers 8 edges per wave instruction (was 4).
// Slot-reduce shfl_xor(8,16,32); softmax across pairs shfl_xor(1,2,4).
// ---------------------------------------------------------------------------
__global__ __launch_bounds__(256) void k_spmm2(const int* __restrict__ offsets,
                                               const int2* __restrict__ sv,
                                               const __half* __restrict__ h2h,
                                               float* __restrict__ out, int n) {
    int t = threadIdx.x;
    int lane = t & 63, wid = t >> 6;
    int dst = blockIdx.x * 4 + wid;
    if (dst >= n) return;
    int e0 = offsets[dst], e1 = offsets[dst + 1];

    int s = lane >> 3;           // edge slot (0..7)
    int p = lane & 7;            // feature pair -> features 2p, 2p+1
    float ax = 0.f, ay = 0.f;
    int e = e0;
    for (; e + 16 <= e1; e += 16) {   // 2 batches in flight
        int2 A0 = sv[e + s];
        int2 A1 = sv[e + 8 + s];
        __half2 g0 = *(const __half2*)&h2h[(size_t)A0.x * D_OUT + 2 * p];
        __half2 g1 = *(const __half2*)&h2h[(size_t)A1.x * D_OUT + 2 * p];
        float v0 = __int_as_float(A0.y), v1 = __int_as_float(A1.y);
        ax = fmaf(v0, __low2float(g0), ax); ay = fmaf(v0, __high2float(g0), ay);
        ax = fmaf(v1, __low2float(g1), ax); ay = fmaf(v1, __high2float(g1), ay);
    }
    for (; e + 8 <= e1; e += 8) {
        int2 A = sv[e + s];
        __half2 g = *(const __half2*)&h2h[(size_t)A.x * D_OUT + 2 * p];
        float v = __int_as_float(A.y);
        ax = fmaf(v, __low2float(g), ax);
        ay = fmaf(v, __high2float(g), ay);
    }
    {   // tail <8 edges, per-slot guard
        int ee = e + s;
        if (ee < e1) {
            int2 A = sv[ee];
            __half2 g = *(const __half2*)&h2h[(size_t)A.x * D_OUT + 2 * p];
            float v = __int_as_float(A.y);
            ax = fmaf(v, __low2float(g), ax);
            ay = fmaf(v, __high2float(g), ay);
        }
    }
    // reduce across 8 edge slots
    ax += __shfl_xor(ax, 8);  ax += __shfl_xor(ax, 16); ax += __shfl_xor(ax, 32);
    ay += __shfl_xor(ay, 8);  ay += __shfl_xor(ay, 16); ay += __shfl_xor(ay, 32);
    // log_softmax across 16 features (pairs in lanes p=0..7)
    float m = fmaxf(ax, ay);
    m = fmaxf(m, __shfl_xor(m, 1));
    m = fmaxf(m, __shfl_xor(m, 2));
    m = fmaxf(m, __shfl_xor(m, 4));
    float sum = expf(ax - m) + expf(ay - m);
    sum += __shfl_xor(sum, 1);
    sum += __shfl_xor(sum, 2);
    sum += __shfl_xor(sum, 4);
    float lg = m + logf(sum);
    if (lane < 8) {
        float2 o = make_float2(ax - lg, ay - lg);
        *(float2*)&out[(size_t)dst * D_OUT + 2 * p] = o;
    }
}

// ---------------------------------------------------------------------------
extern "C" void kernel_launch(void* const* d_in, const int* in_sizes, int n_in,
                              void* d_out, int out_size, void* d_ws, size_t ws_size,
                              hipStream_t stream) {
    const float* x  = (const float*)d_in[0];
    const float* W1 = (const float*)d_in[1];
    const float* W2 = (const float*)d_in[2];
    const float* ev = (const float*)d_in[3];
    const int*   ei = (const int*)d_in[4];
    float* out = (float*)d_out;

    int n     = in_sizes[0] / D_IN;  // 100000
    int e_cnt = in_sizes[3];         // 1600000

    int2*   srcval = (int2*)d_ws;                       // e_cnt
    __half* h1h    = (__half*)(srcval + e_cnt);         // n*64
    __half* h2h    = h1h + (size_t)n * D_H;             // n*16
    int* counts    = (int*)(h2h + (size_t)n * D_OUT);   // n
    int* exOut     = counts + n;                        // n
    int* blockSum  = exOut + n;                         // <=128
    int* blockOff  = blockSum + 128;                    // <=128
    int* offsets   = blockOff + 128;                    // n+1
    int* cursor    = offsets + n + 1;                   // n

    hipMemsetAsync(counts, 0, (size_t)n * sizeof(int), stream);

    int nb_scan = (n + 1023) / 1024;
    int bucketDiv = (n + 7) / 8;         // dst range per XCD pass
    int blocksPerPass = 256;             // grid = 8*256 = 2048 blocks

    k_gemm1  <<<1024, 256, 0, stream>>>(x, W1, h1h, n);
    k_hist   <<<(e_cnt + 255) / 256, 256, 0, stream>>>(ei, counts, e_cnt);
    k_scanA  <<<nb_scan, 256, 0, stream>>>(counts, exOut, blockSum, n);
    k_scanB  <<<1, 128, 0, stream>>>(blockSum, blockOff, offsets, nb_scan, n);
    k_scanC  <<<(n + 255) / 256, 256, 0, stream>>>(exOut, blockOff, offsets, cursor, n);
    k_scatter<<<8 * blocksPerPass, 256, 0, stream>>>(ei, ev, cursor, srcval, e_cnt,
                                                     bucketDiv, blocksPerPass);
    k_spmm1g2<<<(n + 3) / 4, 256, 0, stream>>>(offsets, srcval, h1h, W2, h2h, n);
    k_spmm2  <<<(n + 3) / 4, 256, 0, stream>>>(offsets, srcval, h2h, out, n);
}